// Round 1
// 437.375 us; speedup vs baseline: 1.0512x; 1.0512x over previous
//
#include <hip/hip_runtime.h>
#include <math.h>

#define V_N 100000
#define D_N 300
#define K_N 200
#define B_N 256

#define SC 128.0f
#define SC_INV 0.0078125f

typedef _Float16 h4 __attribute__((ext_vector_type(4)));
typedef _Float16 h8 __attribute__((ext_vector_type(8)));
typedef float f4v __attribute__((ext_vector_type(4)));

typedef __attribute__((address_space(1))) const void gvoid;
typedef __attribute__((address_space(3))) void lvoid;

// ---------------- workspace layout (floats) ----------------
// P  : 20,000,000 (logp, K x V fp32)
// CB : 225,280 floats = 450,560 halves  (LDS image: [kb2][c10]{6 arrays [n112][32] swizzled + pad to 22528 halves})
// scalars: alpha,s,hic,m,z (256 each)
// pm/ps: 800 each (partial softmax stats)
// yF : reuses CB region (halves) after logp is done
static constexpr size_t P_OFF     = 0;
static constexpr size_t CB_OFF    = (size_t)K_N * V_N;            // 20,000,000
static constexpr size_t ALPHA_OFF = CB_OFF + 225280;
static constexpr size_t S_OFF     = ALPHA_OFF + 256;
static constexpr size_t HIC_OFF   = S_OFF + 256;
static constexpr size_t M_OFF     = HIC_OFF + 256;
static constexpr size_t Z_OFF     = M_OFF + 256;
static constexpr size_t PM_OFF    = Z_OFF + 256;
static constexpr size_t PS_OFF    = PM_OFF + 800;
static constexpr size_t YF_OFF    = CB_OFF;   // overlap (halves)

// ---------------- kernel A: per-topic scalars ----------------
__global__ __launch_bounds__(256) void topic_prep(
    const float* __restrict__ mu, const float* __restrict__ w,
    const float* __restrict__ diag,
    float* __restrict__ alpha, float* __restrict__ sArr,
    float* __restrict__ hic)
{
    int k = blockIdx.x;
    int tid = threadIdx.x;
    if (k >= K_N) {
        if (tid == 0) { alpha[k] = 0.f; sArr[k] = 0.f; hic[k] = 0.f; }
        return;
    }
    float capp = 0.f, logd = 0.f, cpart = 0.f, spart = 0.f;
    for (int d = tid; d < D_N; d += 256) {
        float Dg = diag[k * D_N + d];
        float Di = 1.0f / Dg;
        float wvv = w[k * D_N + d];
        float m  = mu[k * D_N + d];
        float u  = wvv * Di;
        capp  += wvv * u;
        logd  += logf(Dg);
        cpart += m * m * Di;
        spart += m * u;
    }
    __shared__ float4 red[256];
    red[tid] = make_float4(capp, logd, cpart, spart);
    __syncthreads();
    for (int s = 128; s > 0; s >>= 1) {
        if (tid < s) {
            float4 a = red[tid], b = red[tid + s];
            red[tid] = make_float4(a.x + b.x, a.y + b.y, a.z + b.z, a.w + b.w);
        }
        __syncthreads();
    }
    if (tid == 0) {
        float4 r = red[0];
        float cap = 1.0f + r.x;
        float logdet = r.y + logf(cap);
        const float LOG2PI = 1.8378770664093453f;
        alpha[k] = -0.5f * ((float)D_N * LOG2PI + logdet + r.z);
        sArr[k]  = r.w;
        hic[k]   = 0.5f / cap;
    }
}

// ---------------- kernel A2: build the B LDS image ----------------
// cB halves: chunk slab (kb,c) = 22528 halves; first 21504 = 6 arrays x [n112][32],
// within row n the four 16B (8-half) blocks are swizzled: pos p holds source
// quad q = (p - (n>>1)) & 3. Tail 1024 halves = zero pad (DMA overrun).
// arr: 0/1 = hi/lo(-0.5*Dinv*SC_INV), 2/3 = hi/lo(mu*Dinv*SC_INV), 4/5 = hi/lo(u*SC_INV)
__global__ __launch_bounds__(256) void coef_prep(
    const float* __restrict__ mu, const float* __restrict__ w,
    const float* __restrict__ cd, _Float16* __restrict__ cB)
{
    int id = blockIdx.x * 256 + threadIdx.x;
    if (id >= 450560) return;
    int chunk = id / 22528;
    int rem   = id % 22528;
    int kb = chunk / 10, c = chunk % 10;
    _Float16 outv = (_Float16)0.f;
    if (rem < 21504) {
        int arr = rem / 3584;
        int r2  = rem % 3584;
        int n = r2 >> 5;
        int h = r2 & 31;
        int p = h >> 3, r = h & 7;
        int q = (p - (n >> 1)) & 3;
        int d = c * 32 + q * 8 + r;
        int topic = kb * 112 + n;
        if (topic < K_N && d < D_N) {
            float Di = 1.0f / cd[topic * D_N + d];
            float val;
            if (arr < 2)      val = -0.5f * Di * SC_INV;
            else if (arr < 4) val = mu[topic * D_N + d] * Di * SC_INV;
            else              val = w[topic * D_N + d] * Di * SC_INV;
            _Float16 hi = (_Float16)val;
            outv = (arr & 1) ? (_Float16)(val - (float)hi) : hi;
        }
    }
    cB[id] = outv;
}

// ---------------- kernel B: logp via split-fp16 MFMA ----------------
// Block tile M=128 (V) x N=112 (topics), 4 waves stacked in M (wave 32x112).
// grid (2 kb, 782 vblk). LDS: As 4 arrays [128][32]h swizzled (32768 B)
//                              Bs 6 arrays [112][32]h swizzled + pad (45056 B)
__global__ __launch_bounds__(256, 2) void logp_mfma(
    const float* __restrict__ wv, const _Float16* __restrict__ cB,
    const float* __restrict__ alphaA, const float* __restrict__ sA,
    const float* __restrict__ hA, float* __restrict__ P)
{
    __shared__ _Float16 smem[38912];   // 77824 B
    _Float16* As = smem;               // arr stride 4096 halves
    _Float16* Bs = smem + 16384;       // arr stride 3584 halves

    const int tid = threadIdx.x;
    const int kb = blockIdx.x;
    const int v0 = blockIdx.y * 128;
    const int lane = tid & 63;
    const int quad = lane >> 4, lr = lane & 15;
    const int wm = (tid >> 6) * 32;
    const int dq = tid & 7, vr = tid >> 3;

    f4v C1[2][7], C2[2][7];
    #pragma unroll
    for (int i = 0; i < 2; ++i)
        #pragma unroll
        for (int j = 0; j < 7; ++j) {
            C1[i][j] = (f4v){0.f, 0.f, 0.f, 0.f};
            C2[i][j] = (f4v){0.f, 0.f, 0.f, 0.f};
        }

    const int row0 = wm + lr, row1 = wm + 16 + lr;
    const int pA = (quad + (row0 >> 1)) & 3;   // same for row1 (row1=row0+16)
    const int offA0 = row0 * 32 + pA * 8;
    const int offA1 = row1 * 32 + pA * 8;

    for (int c = 0; c < 10; ++c) {
        __syncthreads();
        // ---- B: DMA the prebuilt LDS image (11 x 4KB) ----
        {
            const _Float16* slab = cB + (size_t)(kb * 10 + c) * 22528 + tid * 8;
            _Float16* dst = Bs + tid * 8;
            #pragma unroll
            for (int it = 0; it < 11; ++it) {
                __builtin_amdgcn_global_load_lds(
                    (gvoid*)(slab + it * 2048), (lvoid*)(dst + it * 2048),
                    16, 0, 0);
            }
        }
        // ---- A: stage 128 rows x 32 d, fp32 -> 4 split-fp16 arrays ----
        const int d0 = c * 32;
        #pragma unroll
        for (int rep = 0; rep < 4; ++rep) {
            int v = vr + rep * 32;
            int gv = v0 + v;
            int d = d0 + dq * 4;
            float4 a = make_float4(0.f, 0.f, 0.f, 0.f);
            if (gv < V_N && d < D_N)
                a = *(const float4*)(wv + (size_t)gv * D_N + d);
            float av[4] = {a.x, a.y, a.z, a.w};
            h4 ah, al, qh, ql;
            #pragma unroll
            for (int j = 0; j < 4; ++j) {
                float x = av[j];
                _Float16 xh = (_Float16)x;
                ah[j] = xh;
                al[j] = (_Float16)(x - (float)xh);
                float xs = x * x;
                _Float16 sh = (_Float16)xs;
                qh[j] = sh;
                ql[j] = (_Float16)(xs - (float)sh);
            }
            int p = ((dq >> 1) + (v >> 1)) & 3;
            int base = v * 32 + p * 8 + (dq & 1) * 4;
            *(h4*)(As + 0 * 4096 + base) = qh;
            *(h4*)(As + 1 * 4096 + base) = ql;
            *(h4*)(As + 2 * 4096 + base) = ah;
            *(h4*)(As + 3 * 4096 + base) = al;
        }
        __syncthreads();

        // ---- A fragments ----
        h8 fqh0 = *(const h8*)(As + 0 * 4096 + offA0);
        h8 fqh1 = *(const h8*)(As + 0 * 4096 + offA1);
        h8 fql0 = *(const h8*)(As + 1 * 4096 + offA0);
        h8 fql1 = *(const h8*)(As + 1 * 4096 + offA1);
        h8 fah0 = *(const h8*)(As + 2 * 4096 + offA0);
        h8 fah1 = *(const h8*)(As + 2 * 4096 + offA1);
        h8 fal0 = *(const h8*)(As + 3 * 4096 + offA0);
        h8 fal1 = *(const h8*)(As + 3 * 4096 + offA1);

        h8 bf[7];
        #define LDB(arr)                                                       \
            _Pragma("unroll")                                                  \
            for (int nt = 0; nt < 7; ++nt) {                                   \
                int n = nt * 16 + lr;                                          \
                bf[nt] = *(const h8*)(Bs + (arr) * 3584 + n * 32               \
                                      + (((quad + (n >> 1)) & 3) << 3));       \
            }
        #define MF(ACC, MT, FR)                                                \
            _Pragma("unroll")                                                  \
            for (int nt = 0; nt < 7; ++nt)                                     \
                ACC[MT][nt] = __builtin_amdgcn_mfma_f32_16x16x32_f16(          \
                    FR, bf[nt], ACC[MT][nt], 0, 0, 0);

        LDB(0)                    // hi(-0.5 Dinv)
        MF(C1, 0, fqh0) MF(C1, 1, fqh1) MF(C1, 0, fql0) MF(C1, 1, fql1)
        LDB(1)                    // lo(-0.5 Dinv)
        MF(C1, 0, fqh0) MF(C1, 1, fqh1)
        LDB(2)                    // hi(mu Dinv)
        MF(C1, 0, fah0) MF(C1, 1, fah1) MF(C1, 0, fal0) MF(C1, 1, fal1)
        LDB(3)                    // lo(mu Dinv)
        MF(C1, 0, fah0) MF(C1, 1, fah1)
        LDB(4)                    // hi(u)
        MF(C2, 0, fah0) MF(C2, 1, fah1) MF(C2, 0, fal0) MF(C2, 1, fal1)
        LDB(5)                    // lo(u)
        MF(C2, 0, fah0) MF(C2, 1, fah1)
        #undef LDB
        #undef MF
    }

    // ---- epilogue: combine, transpose via LDS, coalesced store ----
    __syncthreads();
    float* Ct = (float*)smem;  // [112][132] fp32 = 59136 B
    #pragma unroll
    for (int nt = 0; nt < 7; ++nt) {
        int nl = nt * 16 + lr;
        int ng = kb * 112 + nl;
        float al = alphaA[ng], sk = sA[ng], hk = hA[ng];
        #pragma unroll
        for (int mt = 0; mt < 2; ++mt) {
            f4v c1 = C1[mt][nt], c2 = C2[mt][nt];
            f4v res;
            #pragma unroll
            for (int r = 0; r < 4; ++r) {
                float t = SC * c2[r] - sk;
                res[r] = al + SC * c1[r] + hk * t * t;
            }
            *(f4v*)(Ct + nl * 132 + wm + mt * 16 + quad * 4) = res;
        }
    }
    __syncthreads();
    #pragma unroll
    for (int i = 0; i < 14; ++i) {
        int id = tid + i * 256;        // 0..3583
        int m4 = (id & 31) * 4;
        int nl = id >> 5;              // 0..111
        int kg = kb * 112 + nl;
        if (kg < K_N) {
            f4v val = *(const f4v*)(Ct + nl * 132 + m4);
            int v = v0 + m4;
            if (v + 3 < V_N) {
                *(float4*)(P + (size_t)kg * V_N + v) =
                    make_float4(val[0], val[1], val[2], val[3]);
            } else {
                for (int j = 0; j < 4; ++j)
                    if (v + j < V_N) P[(size_t)kg * V_N + v + j] = val[j];
            }
        }
    }
}

// ---------------- kernel C: partial softmax stats (4 parts per topic) ------
__global__ __launch_bounds__(256) void softmax_stats(
    const float* __restrict__ P, float* __restrict__ pm,
    float* __restrict__ ps)
{
    int k = blockIdx.x >> 2, part = blockIdx.x & 3;
    int tid = threadIdx.x;
    const float4* row = (const float4*)(P + (size_t)k * V_N) + part * 6250;
    float m = -INFINITY, s = 0.f;
    for (int i = tid; i < 6250; i += 256) {
        float4 x = row[i];
        float mx = fmaxf(fmaxf(x.x, x.y), fmaxf(x.z, x.w));
        if (mx > m) { s *= __expf(m - mx); m = mx; }
        s += __expf(x.x - m) + __expf(x.y - m)
           + __expf(x.z - m) + __expf(x.w - m);
    }
    __shared__ float ms[256], ss[256];
    ms[tid] = m; ss[tid] = s;
    __syncthreads();
    for (int off = 128; off > 0; off >>= 1) {
        if (tid < off) {
            float mo = ms[tid], so = ss[tid];
            float m2 = ms[tid + off], s2 = ss[tid + off];
            float mn = fmaxf(mo, m2);
            ms[tid] = mn;
            ss[tid] = so * __expf(mo - mn) + s2 * __expf(m2 - mn);
        }
        __syncthreads();
    }
    if (tid == 0) { pm[blockIdx.x] = ms[0]; ps[blockIdx.x] = ss[0]; }
}

__global__ __launch_bounds__(256) void stats_merge(
    const float* __restrict__ pm, const float* __restrict__ ps,
    float* __restrict__ mArr, float* __restrict__ zArr)
{
    int k = threadIdx.x;
    if (k < K_N) {
        float m = -INFINITY, s = 0.f;
        #pragma unroll
        for (int p = 0; p < 4; ++p) {
            float m2 = pm[k * 4 + p], s2 = ps[k * 4 + p];
            float mn = fmaxf(m, m2);
            s = s * __expf(m - mn) + s2 * __expf(m2 - mn);
            m = mn;
        }
        mArr[k] = m; zArr[k] = s;
    }
}

// ---------------- kernel C2: yF (MFMA B-layout fp16) + x copy --------------
// yF[kc7][quad4][b256][j8] = x[b][kc*32+quad*8+j] / Z[k]  (0 for k>=200)
__global__ __launch_bounds__(256) void prep_y(
    const float* __restrict__ x, const float* __restrict__ zArr,
    _Float16* __restrict__ yF, float* __restrict__ out)
{
    int id = blockIdx.x * 256 + threadIdx.x;
    if (id < 57344) {
        int j = id & 7;
        int b = (id >> 3) & 255;
        int q = (id >> 11) & 3;
        int kc = id >> 13;
        int k = kc * 32 + q * 8 + j;
        float v = 0.f;
        if (k < K_N) v = x[b * K_N + k] / zArr[k];
        yF[id] = (_Float16)v;
    } else {
        int id2 = id - 57344;
        if (id2 < B_N * K_N) {
            int b = id2 / K_N, k = id2 % K_N;
            out[(size_t)b * (K_N + V_N) + k] = x[id2];
        }
    }
}

// ---------------- kernel D: out = y @ softmax-weights via fp16 MFMA --------
// v2: b-tile = 256 (full B) -> P read from HBM exactly once; exp once per elem.
// Block: v-tile 64 (M, 4 waves x 1 mt), b-tile 256 (N, 16 nt). grid (1563).
// y slab (8192 halves = 16KB per kc) staged to LDS via global_load_lds.
__global__ __launch_bounds__(256) void out_gemm(
    const float* __restrict__ P, const _Float16* __restrict__ yF,
    const float* __restrict__ mArr, float* __restrict__ out)
{
    __shared__ float Es[32][66];        // P chunk minus m_k; stride 66 (2-way reads)
    __shared__ _Float16 Ys[8192];       // y slab for current kc (16 KB)

    const int tid = threadIdx.x;
    const int v0 = blockIdx.x * 64;
    const int lane = tid & 63;
    const int quad = lane >> 4, lr = lane & 15;
    const int w = tid >> 6;
    const int row = w * 16 + lr;        // this wave's v-row within the tile

    f4v acc[16];
    #pragma unroll
    for (int i = 0; i < 16; ++i) acc[i] = (f4v){0.f, 0.f, 0.f, 0.f};

    const int kr = tid >> 3;       // 0..31 (staging row)
    const int vq = tid & 7;

    for (int kc = 0; kc < 7; ++kc) {
        __syncthreads();           // prior compute's LDS reads drained
        // ---- y slab DMA: 8192 halves, linear (layout already MFMA-B) ----
        {
            const _Float16* src = yF + (size_t)kc * 8192 + tid * 8;
            _Float16* dst = Ys + tid * 8;
            #pragma unroll
            for (int it = 0; it < 4; ++it)
                __builtin_amdgcn_global_load_lds(
                    (gvoid*)(src + it * 2048), (lvoid*)(dst + it * 2048),
                    16, 0, 0);
        }
        // ---- stage P chunk (32 k x 64 v), minus m_k ----
        int k = kc * 32 + kr;
        bool kok = k < K_N;
        float mk = kok ? mArr[k] : 0.f;
        #pragma unroll
        for (int i = 0; i < 2; ++i) {
            int vv = (vq + i * 8) * 4;
            float4 pv;
            if (kok && v0 + vv + 3 < V_N) {
                pv = *(const float4*)(P + (size_t)k * V_N + v0 + vv);
                pv = make_float4(pv.x - mk, pv.y - mk, pv.z - mk, pv.w - mk);
            } else {
                pv = make_float4(-1e30f, -1e30f, -1e30f, -1e30f);
            }
            *(float2*)&Es[kr][vv]     = make_float2(pv.x, pv.y);
            *(float2*)&Es[kr][vv + 2] = make_float2(pv.z, pv.w);
        }
        __syncthreads();           // drains DMA (vmcnt) + Es writes

        // ---- B fragments from LDS slab: col b = nt*16+lr, k = quad*8+j ----
        h8 yf[16];
        #pragma unroll
        for (int nt = 0; nt < 16; ++nt)
            yf[nt] = *(const h8*)(Ys + ((size_t)(quad * 256) + nt * 16 + lr) * 8);

        // ---- A fragment: row v = row, k = quad*8+j -> exp + cvt ----
        h8 af;
        #pragma unroll
        for (int j = 0; j < 8; ++j)
            af[j] = (_Float16)__expf(Es[quad * 8 + j][row]);

        #pragma unroll
        for (int nt = 0; nt < 16; ++nt)
            acc[nt] = __builtin_amdgcn_mfma_f32_16x16x32_f16(
                af, yf[nt], acc[nt], 0, 0, 0);
    }

    // store: C row = v (quad*4+reg), col = b (lr)
    int v = v0 + w * 16 + quad * 4;
    #pragma unroll
    for (int nt = 0; nt < 16; ++nt) {
        int b = nt * 16 + lr;
        float* dst = out + (size_t)b * (K_N + V_N) + K_N + v;
        f4v a = acc[nt];
        if (v + 3 < V_N) {
            *(float4*)dst = make_float4(a[0], a[1], a[2], a[3]);
        } else {
            for (int j = 0; j < 4; ++j)
                if (v + j < V_N) dst[j] = a[j];
        }
    }
}

// ---------------- launch ----------------
extern "C" void kernel_launch(void* const* d_in, const int* in_sizes, int n_in,
                              void* d_out, int out_size, void* d_ws, size_t ws_size,
                              hipStream_t stream) {
    const float* x    = (const float*)d_in[0];  // (B, K)
    const float* wv   = (const float*)d_in[1];  // (V, D)
    const float* mu   = (const float*)d_in[2];  // (K, D)
    const float* cw   = (const float*)d_in[3];  // (K, D)
    const float* cd   = (const float*)d_in[4];  // (K, D)
    float* out = (float*)d_out;
    float* ws  = (float*)d_ws;

    float* P      = ws + P_OFF;
    _Float16* cB  = (_Float16*)(ws + CB_OFF);
    float* alpha  = ws + ALPHA_OFF;
    float* sArr   = ws + S_OFF;
    float* hic    = ws + HIC_OFF;
    float* mArr   = ws + M_OFF;
    float* zArr   = ws + Z_OFF;
    float* pm     = ws + PM_OFF;
    float* ps     = ws + PS_OFF;
    _Float16* yF  = (_Float16*)(ws + YF_OFF);   // overlaps cB (post-logp)

    topic_prep<<<256, 256, 0, stream>>>(mu, cw, cd, alpha, sArr, hic);
    coef_prep<<<1760, 256, 0, stream>>>(mu, cw, cd, cB);

    dim3 gB(2, (V_N + 127) / 128);  // (2, 782)
    logp_mfma<<<gB, 256, 0, stream>>>(wv, cB, alpha, sArr, hic, P);

    softmax_stats<<<K_N * 4, 256, 0, stream>>>(P, pm, ps);
    stats_merge<<<1, 256, 0, stream>>>(pm, ps, mArr, zArr);
    prep_y<<<(57344 + B_N * K_N + 255) / 256, 256, 0, stream>>>(x, zArr, yF, out);

    out_gemm<<<(V_N + 63) / 64, 256, 0, stream>>>(P, yF, mArr, out);
}

// Round 2
// 395.631 us; speedup vs baseline: 1.1621x; 1.1055x over previous
//
#include <hip/hip_runtime.h>
#include <math.h>

#define V_N 100000
#define D_N 300
#define K_N 200
#define B_N 256

#define SC 128.0f
#define SC_INV 0.0078125f

typedef _Float16 h4 __attribute__((ext_vector_type(4)));
typedef _Float16 h8 __attribute__((ext_vector_type(8)));
typedef float f4v __attribute__((ext_vector_type(4)));

typedef __attribute__((address_space(1))) const void gvoid;
typedef __attribute__((address_space(3))) void lvoid;

// ---------------- workspace layout (floats) ----------------
// P  : 20,000,000 (logp, K x V fp32)
// CB : 225,280 floats = 450,560 halves  (LDS image: [kb2][c10]{6 arrays [n112][32] swizzled + pad to 22528 halves})
// scalars: alpha,s,hic (256 each)
// pm/ps: 800 each (partial softmax stats)
// yF : reuses CB region (halves) after logp is done
static constexpr size_t P_OFF     = 0;
static constexpr size_t CB_OFF    = (size_t)K_N * V_N;            // 20,000,000
static constexpr size_t ALPHA_OFF = CB_OFF + 225280;
static constexpr size_t S_OFF     = ALPHA_OFF + 256;
static constexpr size_t HIC_OFF   = S_OFF + 256;
static constexpr size_t PM_OFF    = HIC_OFF + 256;
static constexpr size_t PS_OFF    = PM_OFF + 800;
static constexpr size_t YF_OFF    = CB_OFF;   // overlap (halves)

// ---------------- kernel A (fused): per-topic scalars + B LDS image --------
// blocks 0..1759: coef_prep path; blocks 1760..2015: topic_prep path (k = b-1760)
__global__ __launch_bounds__(256) void fused_prep(
    const float* __restrict__ mu, const float* __restrict__ w,
    const float* __restrict__ cd,
    float* __restrict__ alpha, float* __restrict__ sArr,
    float* __restrict__ hic, _Float16* __restrict__ cB)
{
    __shared__ float4 red[256];
    int tid = threadIdx.x;
    if (blockIdx.x < 1760) {
        // ---- coef image: chunk slab (kb,c) = 22528 halves; 6 arrays x [n112][32]
        // swizzled: pos p holds source quad q = (p - (n>>1)) & 3; tail 1024 zero pad.
        // arr: 0/1 = hi/lo(-0.5*Dinv*SC_INV), 2/3 = hi/lo(mu*Dinv*SC_INV), 4/5 = hi/lo(u*SC_INV)
        int id = blockIdx.x * 256 + tid;
        int chunk = id / 22528;
        int rem   = id % 22528;
        int kb = chunk / 10, c = chunk % 10;
        _Float16 outv = (_Float16)0.f;
        if (rem < 21504) {
            int arr = rem / 3584;
            int r2  = rem % 3584;
            int n = r2 >> 5;
            int h = r2 & 31;
            int p = h >> 3, r = h & 7;
            int q = (p - (n >> 1)) & 3;
            int d = c * 32 + q * 8 + r;
            int topic = kb * 112 + n;
            if (topic < K_N && d < D_N) {
                float Di = 1.0f / cd[topic * D_N + d];
                float val;
                if (arr < 2)      val = -0.5f * Di * SC_INV;
                else if (arr < 4) val = mu[topic * D_N + d] * Di * SC_INV;
                else              val = w[topic * D_N + d] * Di * SC_INV;
                _Float16 hi = (_Float16)val;
                outv = (arr & 1) ? (_Float16)(val - (float)hi) : hi;
            }
        }
        cB[id] = outv;
        return;
    }
    // ---- topic scalars ----
    int k = blockIdx.x - 1760;
    if (k >= K_N) {
        if (tid == 0) { alpha[k] = 0.f; sArr[k] = 0.f; hic[k] = 0.f; }
        return;
    }
    float capp = 0.f, logd = 0.f, cpart = 0.f, spart = 0.f;
    for (int d = tid; d < D_N; d += 256) {
        float Dg = cd[k * D_N + d];
        float Di = 1.0f / Dg;
        float wvv = w[k * D_N + d];
        float m  = mu[k * D_N + d];
        float u  = wvv * Di;
        capp  += wvv * u;
        logd  += logf(Dg);
        cpart += m * m * Di;
        spart += m * u;
    }
    red[tid] = make_float4(capp, logd, cpart, spart);
    __syncthreads();
    for (int s = 128; s > 0; s >>= 1) {
        if (tid < s) {
            float4 a = red[tid], b = red[tid + s];
            red[tid] = make_float4(a.x + b.x, a.y + b.y, a.z + b.z, a.w + b.w);
        }
        __syncthreads();
    }
    if (tid == 0) {
        float4 r = red[0];
        float cap = 1.0f + r.x;
        float logdet = r.y + logf(cap);
        const float LOG2PI = 1.8378770664093453f;
        alpha[k] = -0.5f * ((float)D_N * LOG2PI + logdet + r.z);
        sArr[k]  = r.w;
        hic[k]   = 0.5f / cap;
    }
}

// ---------------- kernel B: logp via split-fp16 MFMA (v3) ----------------
// Block tile M=256 (V) x N=112 (topics), 8 waves stacked in M (wave 32x112).
// grid (2 kb, 391 vblk), 512 threads, 1 block/CU.
// A path: per-lane direct global loads -> in-register split-fp16 (no LDS).
// B path: double-buffered LDS slab (2 x 22528 halves = 90112 B) via
// global_load_lds, prefetched one chunk ahead; ONE barrier per chunk.
__global__ __launch_bounds__(512, 2) void logp_mfma(
    const float* __restrict__ wv, const _Float16* __restrict__ cB,
    const float* __restrict__ alphaA, const float* __restrict__ sA,
    const float* __restrict__ hA, float* __restrict__ P)
{
    __shared__ _Float16 smem[45056];   // 90112 B: B slab double buffer

    const int tid = threadIdx.x;
    const int kb = blockIdx.x;
    const int v0 = blockIdx.y * 256;
    const int lane = tid & 63;
    const int quad = lane >> 4, lr = lane & 15;
    const int w = tid >> 6;            // wave 0..7
    const int wm = w * 32;

    const int gv0 = min(v0 + wm + lr,      V_N - 1);
    const int gv1 = min(v0 + wm + 16 + lr, V_N - 1);

    f4v C1[2][7], C2[2][7];
    #pragma unroll
    for (int i = 0; i < 2; ++i)
        #pragma unroll
        for (int j = 0; j < 7; ++j) {
            C1[i][j] = (f4v){0.f, 0.f, 0.f, 0.f};
            C2[i][j] = (f4v){0.f, 0.f, 0.f, 0.f};
        }

    float4 La0, Lb0, La1, Lb1;                 // A prefetch regs (rows row0,row1)
    h8 qh0, ql0, ah0, al0, qh1, ql1, ah1, al1; // A fragments

    auto ISSUE_A = [&](int cn) {
        int db = cn * 32 + (quad << 3);
        int dc = db > 292 ? 292 : db;          // clamp keeps loads in-bounds
        const float* p0 = wv + (size_t)gv0 * D_N + dc;
        const float* p1 = wv + (size_t)gv1 * D_N + dc;
        La0 = *(const float4*)(p0);
        Lb0 = *(const float4*)(p0 + 4);
        La1 = *(const float4*)(p1);
        Lb1 = *(const float4*)(p1 + 4);
    };

    auto ISSUE_B = [&](int cn) {
        const _Float16* slab = cB + (size_t)(kb * 10 + cn) * 22528 + tid * 8;
        _Float16* dst = smem + (cn & 1) * 22528 + tid * 8;
        #pragma unroll
        for (int it = 0; it < 5; ++it)
            __builtin_amdgcn_global_load_lds(
                (gvoid*)(slab + it * 4096), (lvoid*)(dst + it * 4096), 16, 0, 0);
        if (tid < 256)   // wave-uniform tail (waves 0-3)
            __builtin_amdgcn_global_load_lds(
                (gvoid*)(slab + 5 * 4096), (lvoid*)(dst + 5 * 4096), 16, 0, 0);
    };

    auto CVT = [&](int c, const float4& La, const float4& Lb,
                   h8& qh, h8& ql, h8& ah, h8& al) {
        float xr[8];
        xr[0] = La.x; xr[1] = La.y; xr[2] = La.z; xr[3] = La.w;
        xr[4] = Lb.x; xr[5] = Lb.y; xr[6] = Lb.z; xr[7] = Lb.w;
        if (c == 9) {                          // d tail: chunk 9 covers d 288..319
            if (quad == 1) {                   // need 296..299, zero 300..303
                xr[0] = Lb.x; xr[1] = Lb.y; xr[2] = Lb.z; xr[3] = Lb.w;
                xr[4] = 0.f;  xr[5] = 0.f;  xr[6] = 0.f;  xr[7] = 0.f;
            } else if (quad > 1) {             // d >= 304: all zero
                #pragma unroll
                for (int j = 0; j < 8; ++j) xr[j] = 0.f;
            }
        }
        #pragma unroll
        for (int j = 0; j < 8; ++j) {
            float x = xr[j];
            _Float16 xh = (_Float16)x;
            ah[j] = xh;
            al[j] = (_Float16)(x - (float)xh);
            float xs = x * x;
            _Float16 sh = (_Float16)xs;
            qh[j] = sh;
            ql[j] = (_Float16)(xs - (float)sh);
        }
    };

    // prologue: chunk 0 in flight
    ISSUE_A(0);
    ISSUE_B(0);
    __syncthreads();   // drains vmcnt(0): A(0) regs + B(0) slab ready

    for (int c = 0; c < 10; ++c) {
        // convert current A regs -> fragments (frees the prefetch regs)
        CVT(c, La0, Lb0, qh0, ql0, ah0, al0);
        CVT(c, La1, Lb1, qh1, ql1, ah1, al1);
        // prefetch next chunk (hidden under this chunk's compute)
        if (c < 9) {
            ISSUE_A(c + 1);
            ISSUE_B(c + 1);
        }

        const _Float16* Bsp = smem + (c & 1) * 22528;
        h8 bf[7];
        #define LDB(arr)                                                       \
            _Pragma("unroll")                                                  \
            for (int nt = 0; nt < 7; ++nt) {                                   \
                int n = nt * 16 + lr;                                          \
                bf[nt] = *(const h8*)(Bsp + (arr) * 3584 + n * 32              \
                                      + (((quad + (n >> 1)) & 3) << 3));       \
            }
        #define MF(ACC, MT, FR)                                                \
            _Pragma("unroll")                                                  \
            for (int nt = 0; nt < 7; ++nt)                                     \
                ACC[MT][nt] = __builtin_amdgcn_mfma_f32_16x16x32_f16(          \
                    FR, bf[nt], ACC[MT][nt], 0, 0, 0);

        LDB(0)                    // hi(-0.5 Dinv)
        MF(C1, 0, qh0) MF(C1, 1, qh1) MF(C1, 0, ql0) MF(C1, 1, ql1)
        LDB(1)                    // lo(-0.5 Dinv)
        MF(C1, 0, qh0) MF(C1, 1, qh1)
        LDB(2)                    // hi(mu Dinv)
        MF(C1, 0, ah0) MF(C1, 1, ah1) MF(C1, 0, al0) MF(C1, 1, al1)
        LDB(3)                    // lo(mu Dinv)
        MF(C1, 0, ah0) MF(C1, 1, ah1)
        LDB(4)                    // hi(u)
        MF(C2, 0, ah0) MF(C2, 1, ah1) MF(C2, 0, al0) MF(C2, 1, al1)
        LDB(5)                    // lo(u)
        MF(C2, 0, ah0) MF(C2, 1, ah1)
        #undef LDB
        #undef MF

        __syncthreads();  // all waves done with buf (c&1); next chunk's loads drained
    }

    // ---- epilogue: combine, transpose via LDS (2 passes of 128 rows) ----
    float* Ct = (float*)smem;  // [112][132] fp32 = 59136 B
    const int whalf = w >> 2;
    const int wmL = (w & 3) * 32;
    #pragma unroll
    for (int half = 0; half < 2; ++half) {
        if (whalf == half) {
            #pragma unroll
            for (int nt = 0; nt < 7; ++nt) {
                int nl = nt * 16 + lr;
                int ng = kb * 112 + nl;
                float alv = alphaA[ng], sk = sA[ng], hk = hA[ng];
                #pragma unroll
                for (int mt = 0; mt < 2; ++mt) {
                    f4v c1 = C1[mt][nt], c2 = C2[mt][nt];
                    f4v res;
                    #pragma unroll
                    for (int r = 0; r < 4; ++r) {
                        float t = SC * c2[r] - sk;
                        res[r] = alv + SC * c1[r] + hk * t * t;
                    }
                    *(f4v*)(Ct + nl * 132 + wmL + mt * 16 + quad * 4) = res;
                }
            }
        }
        __syncthreads();
        #pragma unroll
        for (int i = 0; i < 7; ++i) {
            int id = tid + i * 512;        // 0..3583
            int m4 = (id & 31) * 4;
            int nl = id >> 5;              // 0..111
            int kg = kb * 112 + nl;
            if (kg < K_N) {
                f4v val = *(const f4v*)(Ct + nl * 132 + m4);
                int v = v0 + half * 128 + m4;
                if (v + 3 < V_N) {
                    *(float4*)(P + (size_t)kg * V_N + v) =
                        make_float4(val[0], val[1], val[2], val[3]);
                } else {
                    for (int j = 0; j < 4; ++j)
                        if (v + j < V_N) P[(size_t)kg * V_N + v + j] = val[j];
                }
            }
        }
        __syncthreads();
    }
}

// ---------------- kernel C: partial softmax stats (4 parts per topic) ------
__global__ __launch_bounds__(256) void softmax_stats(
    const float* __restrict__ P, float* __restrict__ pm,
    float* __restrict__ ps)
{
    int k = blockIdx.x >> 2, part = blockIdx.x & 3;
    int tid = threadIdx.x;
    const float4* row = (const float4*)(P + (size_t)k * V_N) + part * 6250;
    float m = -INFINITY, s = 0.f;
    for (int i = tid; i < 6250; i += 256) {
        float4 x = row[i];
        float mx = fmaxf(fmaxf(x.x, x.y), fmaxf(x.z, x.w));
        if (mx > m) { s *= __expf(m - mx); m = mx; }
        s += __expf(x.x - m) + __expf(x.y - m)
           + __expf(x.z - m) + __expf(x.w - m);
    }
    __shared__ float ms[256], ss[256];
    ms[tid] = m; ss[tid] = s;
    __syncthreads();
    for (int off = 128; off > 0; off >>= 1) {
        if (tid < off) {
            float mo = ms[tid], so = ss[tid];
            float m2 = ms[tid + off], s2 = ss[tid + off];
            float mn = fmaxf(mo, m2);
            ms[tid] = mn;
            ss[tid] = so * __expf(mo - mn) + s2 * __expf(m2 - mn);
        }
        __syncthreads();
    }
    if (tid == 0) { pm[blockIdx.x] = ms[0]; ss[0] = ss[0]; ps[blockIdx.x] = ss[0]; }
}

// ---------------- kernel C2: yF (MFMA B-layout fp16) + x copy --------------
// yF[kc7][quad4][b256][j8] = x[b][kc*32+quad*8+j] / Z[k]  (0 for k>=200)
// Z merged inline from pm/ps (exact same sequential order as old stats_merge).
__global__ __launch_bounds__(256) void prep_y(
    const float* __restrict__ x,
    const float* __restrict__ pm, const float* __restrict__ ps,
    _Float16* __restrict__ yF, float* __restrict__ out)
{
    int id = blockIdx.x * 256 + threadIdx.x;
    if (id < 57344) {
        int j = id & 7;
        int b = (id >> 3) & 255;
        int q = (id >> 11) & 3;
        int kc = id >> 13;
        int k = kc * 32 + q * 8 + j;
        float v = 0.f;
        if (k < K_N) {
            float m = -INFINITY, s = 0.f;
            #pragma unroll
            for (int p = 0; p < 4; ++p) {
                float m2 = pm[k * 4 + p], s2 = ps[k * 4 + p];
                float mn = fmaxf(m, m2);
                s = s * __expf(m - mn) + s2 * __expf(m2 - mn);
                m = mn;
            }
            v = x[b * K_N + k] / s;
        }
        yF[id] = (_Float16)v;
    } else {
        int id2 = id - 57344;
        if (id2 < B_N * K_N) {
            int b = id2 / K_N, k = id2 % K_N;
            out[(size_t)b * (K_N + V_N) + k] = x[id2];
        }
    }
}

// ---------------- kernel D: out = y @ softmax-weights via fp16 MFMA --------
// b-tile = 256 (full B) -> P read from HBM exactly once; exp once per elem.
// Block: v-tile 64 (M, 4 waves x 1 mt), b-tile 256 (N, 16 nt). grid (1563).
// m_k merged inline from pm (max of 4 parts == old sequential merge).
__global__ __launch_bounds__(256) void out_gemm(
    const float* __restrict__ P, const _Float16* __restrict__ yF,
    const float* __restrict__ pm, float* __restrict__ out)
{
    __shared__ float Es[32][66];        // P chunk minus m_k; stride 66 (2-way reads)
    __shared__ _Float16 Ys[8192];       // y slab for current kc (16 KB)

    const int tid = threadIdx.x;
    const int v0 = blockIdx.x * 64;
    const int lane = tid & 63;
    const int quad = lane >> 4, lr = lane & 15;
    const int w = tid >> 6;
    const int row = w * 16 + lr;        // this wave's v-row within the tile

    f4v acc[16];
    #pragma unroll
    for (int i = 0; i < 16; ++i) acc[i] = (f4v){0.f, 0.f, 0.f, 0.f};

    const int kr = tid >> 3;       // 0..31 (staging row)
    const int vq = tid & 7;

    for (int kc = 0; kc < 7; ++kc) {
        __syncthreads();           // prior compute's LDS reads drained
        // ---- y slab DMA: 8192 halves, linear (layout already MFMA-B) ----
        {
            const _Float16* src = yF + (size_t)kc * 8192 + tid * 8;
            _Float16* dst = Ys + tid * 8;
            #pragma unroll
            for (int it = 0; it < 4; ++it)
                __builtin_amdgcn_global_load_lds(
                    (gvoid*)(src + it * 2048), (lvoid*)(dst + it * 2048),
                    16, 0, 0);
        }
        // ---- stage P chunk (32 k x 64 v), minus m_k ----
        int k = kc * 32 + kr;
        bool kok = k < K_N;
        float mk = 0.f;
        if (kok)
            mk = fmaxf(fmaxf(pm[k * 4], pm[k * 4 + 1]),
                       fmaxf(pm[k * 4 + 2], pm[k * 4 + 3]));
        #pragma unroll
        for (int i = 0; i < 2; ++i) {
            int vv = (vq + i * 8) * 4;
            float4 pv;
            if (kok && v0 + vv + 3 < V_N) {
                pv = *(const float4*)(P + (size_t)k * V_N + v0 + vv);
                pv = make_float4(pv.x - mk, pv.y - mk, pv.z - mk, pv.w - mk);
            } else {
                pv = make_float4(-1e30f, -1e30f, -1e30f, -1e30f);
            }
            *(float2*)&Es[kr][vv]     = make_float2(pv.x, pv.y);
            *(float2*)&Es[kr][vv + 2] = make_float2(pv.z, pv.w);
        }
        __syncthreads();           // drains DMA (vmcnt) + Es writes

        // ---- B fragments from LDS slab: col b = nt*16+lr, k = quad*8+j ----
        h8 yf[16];
        #pragma unroll
        for (int nt = 0; nt < 16; ++nt)
            yf[nt] = *(const h8*)(Ys + ((size_t)(quad * 256) + nt * 16 + lr) * 8);

        // ---- A fragment: row v = row, k = quad*8+j -> exp + cvt ----
        h8 af;
        #pragma unroll
        for (int j = 0; j < 8; ++j)
            af[j] = (_Float16)__expf(Es[quad * 8 + j][row]);

        #pragma unroll
        for (int nt = 0; nt < 16; ++nt)
            acc[nt] = __builtin_amdgcn_mfma_f32_16x16x32_f16(
                af, yf[nt], acc[nt], 0, 0, 0);
    }

    // store: C row = v (quad*4+reg), col = b (lr)
    int v = v0 + w * 16 + quad * 4;
    #pragma unroll
    for (int nt = 0; nt < 16; ++nt) {
        int b = nt * 16 + lr;
        float* dst = out + (size_t)b * (K_N + V_N) + K_N + v;
        f4v a = acc[nt];
        if (v + 3 < V_N) {
            *(float4*)dst = make_float4(a[0], a[1], a[2], a[3]);
        } else {
            for (int j = 0; j < 4; ++j)
                if (v + j < V_N) dst[j] = a[j];
        }
    }
}

// ---------------- launch ----------------
extern "C" void kernel_launch(void* const* d_in, const int* in_sizes, int n_in,
                              void* d_out, int out_size, void* d_ws, size_t ws_size,
                              hipStream_t stream) {
    const float* x    = (const float*)d_in[0];  // (B, K)
    const float* wv   = (const float*)d_in[1];  // (V, D)
    const float* mu   = (const float*)d_in[2];  // (K, D)
    const float* cw   = (const float*)d_in[3];  // (K, D)
    const float* cd   = (const float*)d_in[4];  // (K, D)
    float* out = (float*)d_out;
    float* ws  = (float*)d_ws;

    float* P      = ws + P_OFF;
    _Float16* cB  = (_Float16*)(ws + CB_OFF);
    float* alpha  = ws + ALPHA_OFF;
    float* sArr   = ws + S_OFF;
    float* hic    = ws + HIC_OFF;
    float* pm     = ws + PM_OFF;
    float* ps     = ws + PS_OFF;
    _Float16* yF  = (_Float16*)(ws + YF_OFF);   // overlaps cB (post-logp)

    fused_prep<<<2016, 256, 0, stream>>>(mu, cw, cd, alpha, sArr, hic, cB);

    dim3 gB(2, (V_N + 255) / 256);  // (2, 391)
    logp_mfma<<<gB, 512, 0, stream>>>(wv, cB, alpha, sArr, hic, P);

    softmax_stats<<<K_N * 4, 256, 0, stream>>>(P, pm, ps);
    prep_y<<<(57344 + B_N * K_N + 255) / 256, 256, 0, stream>>>(x, pm, ps, yF, out);

    out_gemm<<<(V_N + 63) / 64, 256, 0, stream>>>(P, yF, pm, out);
}